// Round 10
// baseline (490.034 us; speedup 1.0000x reference)
//
#include <hip/hip_runtime.h>
#include <hip/hip_fp16.h>
#include <math.h>

// N=50000, E=800000, G=512, IN=128, HID=32, H1=8, H2=4, OUT=128, D1=256, D2=128

typedef _Float16 f16x8 __attribute__((ext_vector_type(8)));
typedef float f32x4 __attribute__((ext_vector_type(4)));
typedef float f32x2 __attribute__((ext_vector_type(2)));

static __device__ __forceinline__ float h2f(unsigned short u) {
  return __half2float(__builtin_bit_cast(__half, u));
}
static __device__ __forceinline__ unsigned short f2h(float f) {
  return __builtin_bit_cast(unsigned short, __float2half_rn(f));
}
static __device__ __forceinline__ float hlo(unsigned int w) {
  return __low2float(__builtin_bit_cast(__half2, w));
}
static __device__ __forceinline__ float hhi(unsigned int w) {
  return __high2float(__builtin_bit_cast(__half2, w));
}
static __device__ __forceinline__ float wave_sum(float v) {
#pragma unroll
  for (int off = 1; off < 64; off <<= 1) v += __shfl_xor(v, off, 64);
  return v;
}

// ---------------------------------------------------------------------------
// Fused dual f16 MFMA GEMM + attention-logit epilogue + LDS-staged stores.
// C1 = A@B1 (= h, message features) stored FP8 E4M3 (gather traffic halved;
// logits are computed from the fp32 accs so only the aggregated values are
// quantized). C2 = A@B2 + bias2 (= proj residual) stored f16.
template <int K, int C, int H, bool ATOMIC>
__global__ __launch_bounds__(256) void fused_gemm_kernel(
    const unsigned short* __restrict__ A, const unsigned short* __restrict__ Bp1,
    const unsigned short* __restrict__ Bp2, const float* __restrict__ bias2,
    const float* __restrict__ a_src, const float* __restrict__ a_dst,
    unsigned char* __restrict__ C1, unsigned short* __restrict__ C2,
    float* __restrict__ asrc, float* __restrict__ adst, int Ncols) {
  __shared__ unsigned char t1[64 * 72];   // fp8 tile, 8B-aligned rows
  __shared__ unsigned short t2[64 * 72];  // f16 tile, 16B-aligned rows
  const int lane = threadIdx.x & 63;
  const int w = threadIdx.x >> 6;
  const int ml = lane & 15, kq = lane >> 4;
  const int row0 = blockIdx.y * 64 + (w >> 1) * 32;
  const int colt0 = blockIdx.x * 4 + (w & 1) * 2;
  constexpr int KB = K / 32;

  f32x4 w00 = {}, w01 = {}, w10 = {}, w11 = {};
  f32x4 p00 = {}, p01 = {}, p10 = {}, p11 = {};
  const unsigned short* a0 = A + (size_t)(row0 + ml) * K + kq * 8;
  const unsigned short* b1 = Bp1 + ((size_t)colt0 * KB * 64 + lane) * 8;
  const unsigned short* b2 = Bp2 + ((size_t)colt0 * KB * 64 + lane) * 8;
#pragma unroll
  for (int kb = 0; kb < KB; kb++) {
    f16x8 af0 = __builtin_bit_cast(f16x8, *(const uint4*)(a0 + kb * 32));
    f16x8 af1 = __builtin_bit_cast(f16x8, *(const uint4*)(a0 + 16 * K + kb * 32));
    f16x8 bw0 = __builtin_bit_cast(f16x8, *(const uint4*)(b1 + (size_t)kb * 512));
    f16x8 bw1 = __builtin_bit_cast(f16x8, *(const uint4*)(b1 + (size_t)(KB + kb) * 512));
    f16x8 bp0 = __builtin_bit_cast(f16x8, *(const uint4*)(b2 + (size_t)kb * 512));
    f16x8 bp1 = __builtin_bit_cast(f16x8, *(const uint4*)(b2 + (size_t)(KB + kb) * 512));
    w00 = __builtin_amdgcn_mfma_f32_16x16x32_f16(af0, bw0, w00, 0, 0, 0);
    w01 = __builtin_amdgcn_mfma_f32_16x16x32_f16(af0, bw1, w01, 0, 0, 0);
    w10 = __builtin_amdgcn_mfma_f32_16x16x32_f16(af1, bw0, w10, 0, 0, 0);
    w11 = __builtin_amdgcn_mfma_f32_16x16x32_f16(af1, bw1, w11, 0, 0, 0);
    p00 = __builtin_amdgcn_mfma_f32_16x16x32_f16(af0, bp0, p00, 0, 0, 0);
    p01 = __builtin_amdgcn_mfma_f32_16x16x32_f16(af0, bp1, p01, 0, 0, 0);
    p10 = __builtin_amdgcn_mfma_f32_16x16x32_f16(af1, bp0, p10, 0, 0, 0);
    p11 = __builtin_amdgcn_mfma_f32_16x16x32_f16(af1, bp1, p11, 0, 0, 0);
  }
  const int c0 = colt0 * 16 + ml, c1 = c0 + 16;
  const float bi0 = bias2[c0], bi1 = bias2[c1];

  // stage tiles in LDS (C1 as fp8 bytes, C2 as f16)
  const int lr0 = (w >> 1) * 32 + kq * 4;
  const int lc0 = (w & 1) * 32 + ml;
#pragma unroll
  for (int r = 0; r < 4; r++) {
    const unsigned int u0 = __builtin_amdgcn_cvt_pk_fp8_f32(w00[r], w01[r], 0, false);
    const unsigned int u1 = __builtin_amdgcn_cvt_pk_fp8_f32(w10[r], w11[r], 0, false);
    t1[(lr0 + r) * 72 + lc0] = (unsigned char)(u0 & 0xff);
    t1[(lr0 + r) * 72 + lc0 + 16] = (unsigned char)((u0 >> 8) & 0xff);
    t1[(lr0 + 16 + r) * 72 + lc0] = (unsigned char)(u1 & 0xff);
    t1[(lr0 + 16 + r) * 72 + lc0 + 16] = (unsigned char)((u1 >> 8) & 0xff);
    t2[(lr0 + r) * 72 + lc0] = f2h(p00[r] + bi0);
    t2[(lr0 + r) * 72 + lc0 + 16] = f2h(p01[r] + bi1);
    t2[(lr0 + 16 + r) * 72 + lc0] = f2h(p10[r] + bi0);
    t2[(lr0 + 16 + r) * 72 + lc0 + 16] = f2h(p11[r] + bi1);
  }

  // ---- attention-logit epilogue (fp32 accs, exact) ----
  const int hh = (colt0 * 16) / C;
  const float aS0 = a_src[hh * C + (c0 % C)], aS1 = a_src[hh * C + (c1 % C)];
  const float aD0 = a_dst[hh * C + (c0 % C)], aD1 = a_dst[hh * C + (c1 % C)];
  float pS0[4], pD0[4], pS1[4], pD1[4];
#pragma unroll
  for (int r = 0; r < 4; r++) {
    pS0[r] = w00[r] * aS0 + w01[r] * aS1;
    pD0[r] = w00[r] * aD0 + w01[r] * aD1;
    pS1[r] = w10[r] * aS0 + w11[r] * aS1;
    pD1[r] = w10[r] * aD0 + w11[r] * aD1;
  }
#pragma unroll
  for (int off = 1; off < 16; off <<= 1) {
#pragma unroll
    for (int r = 0; r < 4; r++) {
      pS0[r] += __shfl_xor(pS0[r], off);
      pD0[r] += __shfl_xor(pD0[r], off);
      pS1[r] += __shfl_xor(pS1[r], off);
      pD1[r] += __shfl_xor(pD1[r], off);
    }
  }
  if (ml < 4) {
    const int r = ml;
    const int rowA = row0 + kq * 4 + r;
    const int rowB = rowA + 16;
    if constexpr (ATOMIC) {
      atomicAdd(&asrc[rowA * H + hh], pS0[r]);
      atomicAdd(&adst[rowA * H + hh], pD0[r]);
      atomicAdd(&asrc[rowB * H + hh], pS1[r]);
      atomicAdd(&adst[rowB * H + hh], pD1[r]);
    } else {
      asrc[rowA * H + hh] = pS0[r];
      adst[rowA * H + hh] = pD0[r];
      asrc[rowB * H + hh] = pS1[r];
      adst[rowB * H + hh] = pD1[r];
    }
  }

  // ---- coalesced global writes ----
  __syncthreads();
  const int lr = threadIdx.x >> 3;
  const int l8 = threadIdx.x & 7;
#pragma unroll
  for (int pass = 0; pass < 2; pass++) {
    const int row = lr + pass * 32;
    const int grow = blockIdx.y * 64 + row;
    // C1 fp8: 8 B/lane, 64 B/row
    *(uint2*)&C1[(size_t)grow * Ncols + blockIdx.x * 64 + l8 * 8] =
        *(const uint2*)&t1[row * 72 + l8 * 8];
    // C2 f16: 16 B/lane, 128 B/row
    *(uint4*)&C2[(size_t)grow * Ncols + blockIdx.x * 64 + l8 * 8] =
        *(const uint4*)&t2[row * 72 + l8 * 8];
  }
}

// ---------------------------------------------------------------------------
// repack helper: fp32 weight [K][Ncols] -> f16 B-fragment order
static __device__ __forceinline__ void repack_one(const float* B, unsigned short* Bp,
                                                  int K, int Ncols, int idx) {
  const int KB = K >> 5;
  const int lane = idx & 63;
  const int kb = (idx >> 6) % KB;
  const int nt = idx / (KB << 6);
  const int ml = lane & 15, kq = lane >> 4;
  unsigned short* dst = Bp + (size_t)idx * 8;
#pragma unroll
  for (int j = 0; j < 8; j++)
    dst[j] = f2h(B[(size_t)(kb * 32 + kq * 8 + j) * Ncols + nt * 16 + ml]);
}

// ---------------------------------------------------------------------------
// One init kernel: cast x->f16 (+pad rows), zero cnt, zero agg-out pad rows,
// zero L3 logit buffers, repack all 6 weights.
__global__ __launch_bounds__(256) void init_kernel(
    const float* __restrict__ x, unsigned short* __restrict__ xh, int n4, int NN,
    int M64, int pad, int* __restrict__ cnt, unsigned short* __restrict__ big1pad,
    unsigned short* __restrict__ s1pad, float* __restrict__ asrc3,
    float* __restrict__ adst3, const float* W1, const float* pw1, const float* W2,
    const float* pw2, const float* W3, const float* pw3, unsigned short* BpW1,
    unsigned short* BpP1, unsigned short* BpW2, unsigned short* BpP2,
    unsigned short* BpW3, unsigned short* BpP3) {
  int idx = blockIdx.x * 256 + threadIdx.x;
  const int castN = M64 * 32;  // ushort4 units over M64 x 128
  if (idx < castN) {
    ushort4 o;
    if (idx < n4) {
      float4 v = ((const float4*)x)[idx];
      o.x = f2h(v.x); o.y = f2h(v.y); o.z = f2h(v.z); o.w = f2h(v.w);
    } else {
      o.x = o.y = o.z = o.w = 0;
    }
    ((ushort4*)xh)[idx] = o;
    return;
  }
  idx -= castN;
  if (idx < NN) { cnt[idx] = 0; return; }
  idx -= NN;
  if (idx < pad * 32) { ((uint4*)big1pad)[idx] = uint4{0, 0, 0, 0}; return; }
  idx -= pad * 32;
  if (idx < pad * 16) { ((uint4*)s1pad)[idx] = uint4{0, 0, 0, 0}; return; }
  idx -= pad * 16;
  const int zf = M64 / 4;  // float4 units
  if (idx < zf) { ((float4*)asrc3)[idx] = float4{0.f, 0.f, 0.f, 0.f}; return; }
  idx -= zf;
  if (idx < zf) { ((float4*)adst3)[idx] = float4{0.f, 0.f, 0.f, 0.f}; return; }
  idx -= zf;
  if (idx < 4096) { repack_one(W1, BpW1, 128, 256, idx); return; }
  idx -= 4096;
  if (idx < 4096) { repack_one(pw1, BpP1, 128, 256, idx); return; }
  idx -= 4096;
  if (idx < 4096) { repack_one(W2, BpW2, 256, 128, idx); return; }
  idx -= 4096;
  if (idx < 4096) { repack_one(pw2, BpP2, 256, 128, idx); return; }
  idx -= 4096;
  if (idx < 2048) { repack_one(W3, BpW3, 128, 128, idx); return; }
  idx -= 2048;
  if (idx < 2048) repack_one(pw3, BpP3, 128, 128, idx);
}

// ---------------------------------------------------------------------------
// Single-pass GAT aggregate over FP8 message rows (16 B/lane = 16 channels):
//  - direct col loads (same-address broadcast across the RL-lane sub-group)
//  - PD=2 double-buffered prefetch of (col, asrc, h-row16B)
//  - native v_cvt_pk_f32_fp8 decode + fp32 FMA accumulation
// Then bias + LayerNorm + f16 residual + ELU -> f16.
template <int H, int C, int SPLIT>
__global__ __launch_bounds__(256) void gat_agg_kernel(
    const unsigned char* __restrict__ hfeat, const float* __restrict__ asrc,
    const float* __restrict__ adst, const int* __restrict__ rowptr,
    const int* __restrict__ col, const float* __restrict__ bias,
    const float* __restrict__ gamma, const float* __restrict__ beta,
    const unsigned short* __restrict__ proj, unsigned short* __restrict__ out, int N) {
  constexpr int DOUT = H * C;
  constexpr int RL = DOUT / 16;  // lanes covering one fp8 row at 16 B/lane
  static_assert(RL * SPLIT == 64, "bad split");
  constexpr int PD = 2;
  const int wave = threadIdx.x >> 6;
  const int lane = threadIdx.x & 63;
  const int n = blockIdx.x * 4 + wave;
  if (n >= N) return;
  const int rl = lane % RL;
  const int sub = lane / RL;
  const int c0 = rl * 16;  // channel == byte offset
  const int myh = c0 / C;
  const int start = rowptr[n];
  const int deg = rowptr[n + 1] - start;
  const int vlen = deg + 1;
  const int nsteps = (vlen + SPLIT - 1) / SPLIT;
  const int ngroups = (nsteps + PD - 1) / PD;
  const float my_adl = adst[n * H + myh];
  const int clmax = (deg > 0) ? deg - 1 : 0;

  float acc[16];
#pragma unroll
  for (int i = 0; i < 16; i++) acc[i] = 0.f;
  float psum = 0.f;

  float aA[PD], aB[PD];
  uint4 hA[PD], hB[PD];

  auto issue = [&](int g, float* a, uint4* h) {
#pragma unroll
    for (int k = 0; k < PD; k++) {
      const int j = (g * PD + k) * SPLIT + sub;
      int s = col[start + min(j, clmax)];
      s = (j < deg) ? s : n;
      a[k] = asrc[s * H + myh];
      h[k] = *(const uint4*)&hfeat[(size_t)s * DOUT + c0];
    }
  };
  auto consume = [&](int g, const float* a, const uint4* h) {
#pragma unroll
    for (int k = 0; k < PD; k++) {
      const int j = (g * PD + k) * SPLIT + sub;
      float e = a[k] + my_adl;
      e = fmaxf(e, 0.2f * e);
      float p = __expf(e);
      p = (j < vlen) ? p : 0.f;
      psum += p;
      f32x2 f;
      f = __builtin_amdgcn_cvt_pk_f32_fp8(h[k].x, false);
      acc[0] += f.x * p; acc[1] += f.y * p;
      f = __builtin_amdgcn_cvt_pk_f32_fp8(h[k].x, true);
      acc[2] += f.x * p; acc[3] += f.y * p;
      f = __builtin_amdgcn_cvt_pk_f32_fp8(h[k].y, false);
      acc[4] += f.x * p; acc[5] += f.y * p;
      f = __builtin_amdgcn_cvt_pk_f32_fp8(h[k].y, true);
      acc[6] += f.x * p; acc[7] += f.y * p;
      f = __builtin_amdgcn_cvt_pk_f32_fp8(h[k].z, false);
      acc[8] += f.x * p; acc[9] += f.y * p;
      f = __builtin_amdgcn_cvt_pk_f32_fp8(h[k].z, true);
      acc[10] += f.x * p; acc[11] += f.y * p;
      f = __builtin_amdgcn_cvt_pk_f32_fp8(h[k].w, false);
      acc[12] += f.x * p; acc[13] += f.y * p;
      f = __builtin_amdgcn_cvt_pk_f32_fp8(h[k].w, true);
      acc[14] += f.x * p; acc[15] += f.y * p;
    }
  };

  issue(0, aA, hA);
  for (int g = 0; g < ngroups; g += 2) {
    if (g + 1 < ngroups) issue(g + 1, aB, hB);
    consume(g, aA, hA);
    if (g + 1 < ngroups) {
      if (g + 2 < ngroups) issue(g + 2, aA, hA);
      consume(g + 1, aB, hB);
    }
  }

  // combine SPLIT sub-wave partials
#pragma unroll
  for (int o = RL; o < 64; o <<= 1) {
    psum += __shfl_xor(psum, o);
#pragma unroll
    for (int i = 0; i < 16; i++) acc[i] += __shfl_xor(acc[i], o);
  }

  const float rs = 1.f / (psum + 1e-16f);
  float v[16];
#pragma unroll
  for (int q = 0; q < 4; q++) {
    const float4 bi = *(const float4*)&bias[c0 + q * 4];
    v[q * 4 + 0] = acc[q * 4 + 0] * rs + bi.x;
    v[q * 4 + 1] = acc[q * 4 + 1] * rs + bi.y;
    v[q * 4 + 2] = acc[q * 4 + 2] * rs + bi.z;
    v[q * 4 + 3] = acc[q * 4 + 3] * rs + bi.w;
  }
  float s16 = 0.f;
#pragma unroll
  for (int i = 0; i < 16; i++) s16 += v[i];
  const float mean = wave_sum(s16) / (float)(DOUT * SPLIT);
  float q16 = 0.f;
#pragma unroll
  for (int i = 0; i < 16; i++) {
    v[i] -= mean;
    q16 += v[i] * v[i];
  }
  const float var = wave_sum(q16) / (float)(DOUT * SPLIT);
  const float rstd = rsqrtf(var + 1e-5f);

  const uint4 pr0 = *(const uint4*)&proj[(size_t)n * DOUT + c0];
  const uint4 pr1 = *(const uint4*)&proj[(size_t)n * DOUT + c0 + 8];
  float pres[16];
  pres[0] = hlo(pr0.x); pres[1] = hhi(pr0.x); pres[2] = hlo(pr0.y); pres[3] = hhi(pr0.y);
  pres[4] = hlo(pr0.z); pres[5] = hhi(pr0.z); pres[6] = hlo(pr0.w); pres[7] = hhi(pr0.w);
  pres[8] = hlo(pr1.x); pres[9] = hhi(pr1.x); pres[10] = hlo(pr1.y); pres[11] = hhi(pr1.y);
  pres[12] = hlo(pr1.z); pres[13] = hhi(pr1.z); pres[14] = hlo(pr1.w); pres[15] = hhi(pr1.w);

  float o16[16];
#pragma unroll
  for (int q = 0; q < 4; q++) {
    const float4 ga = *(const float4*)&gamma[c0 + q * 4];
    const float4 be = *(const float4*)&beta[c0 + q * 4];
    o16[q * 4 + 0] = v[q * 4 + 0] * rstd * ga.x + be.x + pres[q * 4 + 0];
    o16[q * 4 + 1] = v[q * 4 + 1] * rstd * ga.y + be.y + pres[q * 4 + 1];
    o16[q * 4 + 2] = v[q * 4 + 2] * rstd * ga.z + be.z + pres[q * 4 + 2];
    o16[q * 4 + 3] = v[q * 4 + 3] * rstd * ga.w + be.w + pres[q * 4 + 3];
  }
#pragma unroll
  for (int i = 0; i < 16; i++)
    o16[i] = (o16[i] > 0.f) ? o16[i] : (__expf(o16[i]) - 1.f);  // ELU

  if (sub == 0) {
    uint4 ov0, ov1;
    ov0.x = (unsigned int)f2h(o16[0]) | ((unsigned int)f2h(o16[1]) << 16);
    ov0.y = (unsigned int)f2h(o16[2]) | ((unsigned int)f2h(o16[3]) << 16);
    ov0.z = (unsigned int)f2h(o16[4]) | ((unsigned int)f2h(o16[5]) << 16);
    ov0.w = (unsigned int)f2h(o16[6]) | ((unsigned int)f2h(o16[7]) << 16);
    ov1.x = (unsigned int)f2h(o16[8]) | ((unsigned int)f2h(o16[9]) << 16);
    ov1.y = (unsigned int)f2h(o16[10]) | ((unsigned int)f2h(o16[11]) << 16);
    ov1.z = (unsigned int)f2h(o16[12]) | ((unsigned int)f2h(o16[13]) << 16);
    ov1.w = (unsigned int)f2h(o16[14]) | ((unsigned int)f2h(o16[15]) << 16);
    *(uint4*)&out[(size_t)n * DOUT + c0] = ov0;
    *(uint4*)&out[(size_t)n * DOUT + c0 + 8] = ov1;
  }
}

// ---------------------------------------------------------------------------
// CSR build
__global__ void hist_kernel(const int* __restrict__ dst, int* __restrict__ cnt, int E) {
  const int e = blockIdx.x * 256 + threadIdx.x;
  if (e < E) atomicAdd(&cnt[dst[e]], 1);
}

__global__ __launch_bounds__(256) void scan1_kernel(int* __restrict__ cnt,
                                                    int* __restrict__ sums, int N) {
  __shared__ int sm[256];
  const int i = blockIdx.x * 256 + threadIdx.x;
  const int v = (i < N) ? cnt[i] : 0;
  sm[threadIdx.x] = v;
  __syncthreads();
  for (int off = 1; off < 256; off <<= 1) {
    const int t = (threadIdx.x >= off) ? sm[threadIdx.x - off] : 0;
    __syncthreads();
    sm[threadIdx.x] += t;
    __syncthreads();
  }
  if (i < N) cnt[i] = sm[threadIdx.x] - v;  // exclusive within block
  if (threadIdx.x == 255) sums[blockIdx.x] = sm[255];
}

// fused scan2+scan3: every block locally scans the block sums, then emits rowptr
__global__ __launch_bounds__(256) void scan23_kernel(const int* __restrict__ cnt,
                                                     const int* __restrict__ sums,
                                                     int* __restrict__ rowptr,
                                                     int* __restrict__ cursor, int N,
                                                     int E, int nb) {
  __shared__ int sm[256];
  const int v = (threadIdx.x < nb) ? sums[threadIdx.x] : 0;
  sm[threadIdx.x] = v;
  __syncthreads();
  for (int off = 1; off < 256; off <<= 1) {
    const int t = (threadIdx.x >= off) ? sm[threadIdx.x - off] : 0;
    __syncthreads();
    sm[threadIdx.x] += t;
    __syncthreads();
  }
  const int base = (blockIdx.x == 0) ? 0 : sm[blockIdx.x - 1];  // exclusive
  const int i = blockIdx.x * 256 + threadIdx.x;
  if (i < N) {
    const int r = cnt[i] + base;
    rowptr[i] = r;
    cursor[i] = r;
  }
  if (i == 0) rowptr[N] = E;
}

__global__ void scatter_kernel(const int* __restrict__ src, const int* __restrict__ dst,
                               int* __restrict__ cursor, int* __restrict__ col, int E) {
  const int e = blockIdx.x * 256 + threadIdx.x;
  if (e < E) {
    const int p = atomicAdd(&cursor[dst[e]], 1);
    col[p] = src[e];
  }
}

// ---------------------------------------------------------------------------
// Global mean pool per graph (batch sorted): one block per graph.
__global__ __launch_bounds__(128) void pool_kernel(const unsigned short* __restrict__ h3,
                                                   const int* __restrict__ batch,
                                                   float* __restrict__ out, int N) {
  __shared__ int sse[2];
  const int g = blockIdx.x;
  if (threadIdx.x == 0) {
    int lo = 0, hi = N;
    while (lo < hi) { const int mid = (lo + hi) >> 1; if (batch[mid] < g) lo = mid + 1; else hi = mid; }
    sse[0] = lo;
    lo = 0; hi = N;
    while (lo < hi) { const int mid = (lo + hi) >> 1; if (batch[mid] < g + 1) lo = mid + 1; else hi = mid; }
    sse[1] = lo;
  }
  __syncthreads();
  const int s = sse[0], e = sse[1];
  float sum = 0.f;
  for (int r = s; r < e; r++) sum += h2f(h3[(size_t)r * 128 + threadIdx.x]);
  out[g * 128 + threadIdx.x] = (e > s) ? sum / (float)(e - s) : 0.f;
}

// ---------------------------------------------------------------------------
extern "C" void kernel_launch(void* const* d_in, const int* in_sizes, int n_in,
                              void* d_out, int out_size, void* d_ws, size_t ws_size,
                              hipStream_t stream) {
  const float* x      = (const float*)d_in[0];
  const int* edge_idx = (const int*)d_in[1];
  const int* batch    = (const int*)d_in[2];
  const float* W1     = (const float*)d_in[3];
  const float* a_src1 = (const float*)d_in[4];
  const float* a_dst1 = (const float*)d_in[5];
  const float* b1     = (const float*)d_in[6];
  const float* g1     = (const float*)d_in[7];
  const float* be1    = (const float*)d_in[8];
  const float* pw1    = (const float*)d_in[9];
  const float* pb1    = (const float*)d_in[10];
  const float* W2     = (const float*)d_in[11];
  const float* a_src2 = (const float*)d_in[12];
  const float* a_dst2 = (const float*)d_in[13];
  const float* b2     = (const float*)d_in[14];
  const float* g2     = (const float*)d_in[15];
  const float* be2    = (const float*)d_in[16];
  const float* pw2    = (const float*)d_in[17];
  const float* pb2    = (const float*)d_in[18];
  const float* W3     = (const float*)d_in[19];
  const float* a_src3 = (const float*)d_in[20];
  const float* a_dst3 = (const float*)d_in[21];
  const float* b3     = (const float*)d_in[22];
  const float* g3     = (const float*)d_in[23];
  const float* be3    = (const float*)d_in[24];
  const float* pw3    = (const float*)d_in[25];
  const float* pb3    = (const float*)d_in[26];

  const int NN = in_sizes[0] / 128;  // 50000
  const int E  = in_sizes[1] / 2;    // 800000
  const int G  = out_size / 128;     // 512
  const int M64 = (NN + 63) & ~63;   // 50048

  size_t off = 0;
  auto alloc = [&](size_t bytes) {
    size_t r = off;
    off += (bytes + 255) & ~(size_t)255;
    return r;
  };
  char* ws = (char*)d_ws;
  unsigned char* hf    = (unsigned char*)(ws + alloc((size_t)M64 * 256));      // fp8 msg features (all layers)
  unsigned short* big1 = (unsigned short*)(ws + alloc((size_t)M64 * 256 * 2)); // h1out f16
  unsigned short* s0   = (unsigned short*)(ws + alloc((size_t)M64 * 128 * 2)); // xh / h3out f16
  unsigned short* s1   = (unsigned short*)(ws + alloc((size_t)M64 * 128 * 2)); // h2out f16
  unsigned short* projb = (unsigned short*)(ws + alloc((size_t)M64 * 256 * 2)); // f16 residual
  float* asrcB  = (float*)(ws + alloc((size_t)M64 * 8 * 4));
  float* adstB  = (float*)(ws + alloc((size_t)M64 * 8 * 4));
  float* asrc3B = (float*)(ws + alloc((size_t)M64 * 4));
  float* adst3B = (float*)(ws + alloc((size_t)M64 * 4));
  int* rowptr  = (int*)(ws + alloc((size_t)(NN + 1) * 4));
  int* cnt     = (int*)(ws + alloc((size_t)NN * 4));
  int* cursor  = (int*)(ws + alloc((size_t)NN * 4));
  int* colb    = (int*)(ws + alloc((size_t)(E + 64) * 4));  // +64 pad: clamped OOB reads
  int* sums    = (int*)(ws + alloc(256 * 4));
  unsigned short* BpW1 = (unsigned short*)(ws + alloc(128 * 256 * 2));
  unsigned short* BpP1 = (unsigned short*)(ws + alloc(128 * 256 * 2));
  unsigned short* BpW2 = (unsigned short*)(ws + alloc(256 * 128 * 2));
  unsigned short* BpP2 = (unsigned short*)(ws + alloc(256 * 128 * 2));
  unsigned short* BpW3 = (unsigned short*)(ws + alloc(128 * 128 * 2));
  unsigned short* BpP3 = (unsigned short*)(ws + alloc(128 * 128 * 2));
  (void)ws_size; (void)n_in;

  const int EB = (E + 255) / 256;
  const int NB = (NN + 255) / 256;  // 196
  const int NW = (NN + 3) / 4;
  const int MB = M64 / 64;
  const int pad = M64 - NN;

  // ---- init: cast + all zeroing + all repacks in one dispatch ----
  const int initN = M64 * 32 + NN + pad * 32 + pad * 16 + 2 * (M64 / 4) + 20480;
  init_kernel<<<(initN + 255) / 256, 256, 0, stream>>>(
      x, s0, NN * 32, NN, M64, pad, cnt, big1 + (size_t)NN * 256,
      s1 + (size_t)NN * 128, asrc3B, adst3B, W1, pw1, W2, pw2, W3, pw3, BpW1, BpP1,
      BpW2, BpP2, BpW3, BpP3);

  // ---- CSR build (dst-sorted adjacency), reused by all 3 layers ----
  hist_kernel<<<EB, 256, 0, stream>>>(edge_idx + E, cnt, E);
  scan1_kernel<<<NB, 256, 0, stream>>>(cnt, sums, NN);
  scan23_kernel<<<NB, 256, 0, stream>>>(cnt, sums, rowptr, cursor, NN, E, NB);
  scatter_kernel<<<EB, 256, 0, stream>>>(edge_idx, edge_idx + E, cursor, colb, E);

  // ---- Layer 1: 128 -> 8x32 = 256 ----
  fused_gemm_kernel<128, 32, 8, false><<<dim3(4, MB), 256, 0, stream>>>(
      s0, BpW1, BpP1, pb1, a_src1, a_dst1, hf, projb, asrcB, adstB, 256);
  gat_agg_kernel<8, 32, 4><<<NW, 256, 0, stream>>>(hf, asrcB, adstB, rowptr, colb,
                                                   b1, g1, be1, projb, big1, NN);
  // big1 = h1 (f16)

  // ---- Layer 2: 256 -> 4x32 = 128 ----
  fused_gemm_kernel<256, 32, 4, false><<<dim3(2, MB), 256, 0, stream>>>(
      big1, BpW2, BpP2, pb2, a_src2, a_dst2, hf, projb, asrcB, adstB, 128);
  gat_agg_kernel<4, 32, 8><<<NW, 256, 0, stream>>>(hf, asrcB, adstB, rowptr, colb,
                                                   b2, g2, be2, projb, s1, NN);
  // s1 = h2 (f16)

  // ---- Layer 3: 128 -> 1x128 (concat=False; 1 head -> identity mean) ----
  fused_gemm_kernel<128, 128, 1, true><<<dim3(2, MB), 256, 0, stream>>>(
      s1, BpW3, BpP3, pb3, a_src3, a_dst3, hf, projb, asrc3B, adst3B, 128);
  gat_agg_kernel<1, 128, 8><<<NW, 256, 0, stream>>>(hf, asrc3B, adst3B, rowptr, colb,
                                                    b3, g3, be3, projb, s0, NN);
  // s0 = h3 (f16)

  // ---- Global mean pool per graph ----
  pool_kernel<<<G, 128, 0, stream>>>(s0, batch, (float*)d_out, NN);
}

// Round 11
// 461.063 us; speedup vs baseline: 1.0628x; 1.0628x over previous
//
#include <hip/hip_runtime.h>
#include <hip/hip_fp16.h>
#include <math.h>

// N=50000, E=800000, G=512, IN=128, HID=32, H1=8, H2=4, OUT=128, D1=256, D2=128

typedef _Float16 f16x8 __attribute__((ext_vector_type(8)));
typedef float f32x4 __attribute__((ext_vector_type(4)));
typedef float f32x2 __attribute__((ext_vector_type(2)));

static __device__ __forceinline__ float h2f(unsigned short u) {
  return __half2float(__builtin_bit_cast(__half, u));
}
static __device__ __forceinline__ unsigned short f2h(float f) {
  return __builtin_bit_cast(unsigned short, __float2half_rn(f));
}
static __device__ __forceinline__ float hlo(unsigned int w) {
  return __low2float(__builtin_bit_cast(__half2, w));
}
static __device__ __forceinline__ float hhi(unsigned int w) {
  return __high2float(__builtin_bit_cast(__half2, w));
}
static __device__ __forceinline__ float wave_sum(float v) {
#pragma unroll
  for (int off = 1; off < 64; off <<= 1) v += __shfl_xor(v, off, 64);
  return v;
}

// ---------------------------------------------------------------------------
// Fused dual f16 MFMA GEMM + attention-logit epilogue + LDS-staged stores.
// C1 = A@B1 (= h, message features) stored FP8 E4M3; C2 = A@B2 + bias2 f16.
template <int K, int C, int H, bool ATOMIC>
__global__ __launch_bounds__(256) void fused_gemm_kernel(
    const unsigned short* __restrict__ A, const unsigned short* __restrict__ Bp1,
    const unsigned short* __restrict__ Bp2, const float* __restrict__ bias2,
    const float* __restrict__ a_src, const float* __restrict__ a_dst,
    unsigned char* __restrict__ C1, unsigned short* __restrict__ C2,
    float* __restrict__ asrc, float* __restrict__ adst, int Ncols) {
  __shared__ unsigned char t1[64 * 72];   // fp8 tile, 8B-aligned rows
  __shared__ unsigned short t2[64 * 72];  // f16 tile, 16B-aligned rows
  const int lane = threadIdx.x & 63;
  const int w = threadIdx.x >> 6;
  const int ml = lane & 15, kq = lane >> 4;
  const int row0 = blockIdx.y * 64 + (w >> 1) * 32;
  const int colt0 = blockIdx.x * 4 + (w & 1) * 2;
  constexpr int KB = K / 32;

  f32x4 w00 = {}, w01 = {}, w10 = {}, w11 = {};
  f32x4 p00 = {}, p01 = {}, p10 = {}, p11 = {};
  const unsigned short* a0 = A + (size_t)(row0 + ml) * K + kq * 8;
  const unsigned short* b1 = Bp1 + ((size_t)colt0 * KB * 64 + lane) * 8;
  const unsigned short* b2 = Bp2 + ((size_t)colt0 * KB * 64 + lane) * 8;
#pragma unroll
  for (int kb = 0; kb < KB; kb++) {
    f16x8 af0 = __builtin_bit_cast(f16x8, *(const uint4*)(a0 + kb * 32));
    f16x8 af1 = __builtin_bit_cast(f16x8, *(const uint4*)(a0 + 16 * K + kb * 32));
    f16x8 bw0 = __builtin_bit_cast(f16x8, *(const uint4*)(b1 + (size_t)kb * 512));
    f16x8 bw1 = __builtin_bit_cast(f16x8, *(const uint4*)(b1 + (size_t)(KB + kb) * 512));
    f16x8 bp0 = __builtin_bit_cast(f16x8, *(const uint4*)(b2 + (size_t)kb * 512));
    f16x8 bp1 = __builtin_bit_cast(f16x8, *(const uint4*)(b2 + (size_t)(KB + kb) * 512));
    w00 = __builtin_amdgcn_mfma_f32_16x16x32_f16(af0, bw0, w00, 0, 0, 0);
    w01 = __builtin_amdgcn_mfma_f32_16x16x32_f16(af0, bw1, w01, 0, 0, 0);
    w10 = __builtin_amdgcn_mfma_f32_16x16x32_f16(af1, bw0, w10, 0, 0, 0);
    w11 = __builtin_amdgcn_mfma_f32_16x16x32_f16(af1, bw1, w11, 0, 0, 0);
    p00 = __builtin_amdgcn_mfma_f32_16x16x32_f16(af0, bp0, p00, 0, 0, 0);
    p01 = __builtin_amdgcn_mfma_f32_16x16x32_f16(af0, bp1, p01, 0, 0, 0);
    p10 = __builtin_amdgcn_mfma_f32_16x16x32_f16(af1, bp0, p10, 0, 0, 0);
    p11 = __builtin_amdgcn_mfma_f32_16x16x32_f16(af1, bp1, p11, 0, 0, 0);
  }
  const int c0 = colt0 * 16 + ml, c1 = c0 + 16;
  const float bi0 = bias2[c0], bi1 = bias2[c1];

  // stage tiles in LDS (C1 as fp8 bytes, C2 as f16)
  const int lr0 = (w >> 1) * 32 + kq * 4;
  const int lc0 = (w & 1) * 32 + ml;
#pragma unroll
  for (int r = 0; r < 4; r++) {
    const unsigned int u0 = __builtin_amdgcn_cvt_pk_fp8_f32(w00[r], w01[r], 0, false);
    const unsigned int u1 = __builtin_amdgcn_cvt_pk_fp8_f32(w10[r], w11[r], 0, false);
    t1[(lr0 + r) * 72 + lc0] = (unsigned char)(u0 & 0xff);
    t1[(lr0 + r) * 72 + lc0 + 16] = (unsigned char)((u0 >> 8) & 0xff);
    t1[(lr0 + 16 + r) * 72 + lc0] = (unsigned char)(u1 & 0xff);
    t1[(lr0 + 16 + r) * 72 + lc0 + 16] = (unsigned char)((u1 >> 8) & 0xff);
    t2[(lr0 + r) * 72 + lc0] = f2h(p00[r] + bi0);
    t2[(lr0 + r) * 72 + lc0 + 16] = f2h(p01[r] + bi1);
    t2[(lr0 + 16 + r) * 72 + lc0] = f2h(p10[r] + bi0);
    t2[(lr0 + 16 + r) * 72 + lc0 + 16] = f2h(p11[r] + bi1);
  }

  // ---- attention-logit epilogue (fp32 accs, exact) ----
  const int hh = (colt0 * 16) / C;
  const float aS0 = a_src[hh * C + (c0 % C)], aS1 = a_src[hh * C + (c1 % C)];
  const float aD0 = a_dst[hh * C + (c0 % C)], aD1 = a_dst[hh * C + (c1 % C)];
  float pS0[4], pD0[4], pS1[4], pD1[4];
#pragma unroll
  for (int r = 0; r < 4; r++) {
    pS0[r] = w00[r] * aS0 + w01[r] * aS1;
    pD0[r] = w00[r] * aD0 + w01[r] * aD1;
    pS1[r] = w10[r] * aS0 + w11[r] * aS1;
    pD1[r] = w10[r] * aD0 + w11[r] * aD1;
  }
#pragma unroll
  for (int off = 1; off < 16; off <<= 1) {
#pragma unroll
    for (int r = 0; r < 4; r++) {
      pS0[r] += __shfl_xor(pS0[r], off);
      pD0[r] += __shfl_xor(pD0[r], off);
      pS1[r] += __shfl_xor(pS1[r], off);
      pD1[r] += __shfl_xor(pD1[r], off);
    }
  }
  if (ml < 4) {
    const int r = ml;
    const int rowA = row0 + kq * 4 + r;
    const int rowB = rowA + 16;
    if constexpr (ATOMIC) {
      atomicAdd(&asrc[rowA * H + hh], pS0[r]);
      atomicAdd(&adst[rowA * H + hh], pD0[r]);
      atomicAdd(&asrc[rowB * H + hh], pS1[r]);
      atomicAdd(&adst[rowB * H + hh], pD1[r]);
    } else {
      asrc[rowA * H + hh] = pS0[r];
      adst[rowA * H + hh] = pD0[r];
      asrc[rowB * H + hh] = pS1[r];
      adst[rowB * H + hh] = pD1[r];
    }
  }

  // ---- coalesced global writes ----
  __syncthreads();
  const int lr = threadIdx.x >> 3;
  const int l8 = threadIdx.x & 7;
#pragma unroll
  for (int pass = 0; pass < 2; pass++) {
    const int row = lr + pass * 32;
    const int grow = blockIdx.y * 64 + row;
    *(uint2*)&C1[(size_t)grow * Ncols + blockIdx.x * 64 + l8 * 8] =
        *(const uint2*)&t1[row * 72 + l8 * 8];
    *(uint4*)&C2[(size_t)grow * Ncols + blockIdx.x * 64 + l8 * 8] =
        *(const uint4*)&t2[row * 72 + l8 * 8];
  }
}

// ---------------------------------------------------------------------------
// repack helper: fp32 weight [K][Ncols] -> f16 B-fragment order
static __device__ __forceinline__ void repack_one(const float* B, unsigned short* Bp,
                                                  int K, int Ncols, int idx) {
  const int KB = K >> 5;
  const int lane = idx & 63;
  const int kb = (idx >> 6) % KB;
  const int nt = idx / (KB << 6);
  const int ml = lane & 15, kq = lane >> 4;
  unsigned short* dst = Bp + (size_t)idx * 8;
#pragma unroll
  for (int j = 0; j < 8; j++)
    dst[j] = f2h(B[(size_t)(kb * 32 + kq * 8 + j) * Ncols + nt * 16 + ml]);
}

// ---------------------------------------------------------------------------
// One init kernel: cast x->f16 (+pad rows), zero cnt, zero agg-out pad rows,
// zero L3 logit buffers, repack all 6 weights.
__global__ __launch_bounds__(256) void init_kernel(
    const float* __restrict__ x, unsigned short* __restrict__ xh, int n4, int NN,
    int M64, int pad, int* __restrict__ cnt, unsigned short* __restrict__ big1pad,
    unsigned short* __restrict__ s1pad, float* __restrict__ asrc3,
    float* __restrict__ adst3, const float* W1, const float* pw1, const float* W2,
    const float* pw2, const float* W3, const float* pw3, unsigned short* BpW1,
    unsigned short* BpP1, unsigned short* BpW2, unsigned short* BpP2,
    unsigned short* BpW3, unsigned short* BpP3) {
  int idx = blockIdx.x * 256 + threadIdx.x;
  const int castN = M64 * 32;  // ushort4 units over M64 x 128
  if (idx < castN) {
    ushort4 o;
    if (idx < n4) {
      float4 v = ((const float4*)x)[idx];
      o.x = f2h(v.x); o.y = f2h(v.y); o.z = f2h(v.z); o.w = f2h(v.w);
    } else {
      o.x = o.y = o.z = o.w = 0;
    }
    ((ushort4*)xh)[idx] = o;
    return;
  }
  idx -= castN;
  if (idx < NN) { cnt[idx] = 0; return; }
  idx -= NN;
  if (idx < pad * 32) { ((uint4*)big1pad)[idx] = uint4{0, 0, 0, 0}; return; }
  idx -= pad * 32;
  if (idx < pad * 16) { ((uint4*)s1pad)[idx] = uint4{0, 0, 0, 0}; return; }
  idx -= pad * 16;
  const int zf = M64 / 4;  // float4 units
  if (idx < zf) { ((float4*)asrc3)[idx] = float4{0.f, 0.f, 0.f, 0.f}; return; }
  idx -= zf;
  if (idx < zf) { ((float4*)adst3)[idx] = float4{0.f, 0.f, 0.f, 0.f}; return; }
  idx -= zf;
  if (idx < 4096) { repack_one(W1, BpW1, 128, 256, idx); return; }
  idx -= 4096;
  if (idx < 4096) { repack_one(pw1, BpP1, 128, 256, idx); return; }
  idx -= 4096;
  if (idx < 4096) { repack_one(W2, BpW2, 256, 128, idx); return; }
  idx -= 4096;
  if (idx < 4096) { repack_one(pw2, BpP2, 256, 128, idx); return; }
  idx -= 4096;
  if (idx < 2048) { repack_one(W3, BpW3, 128, 128, idx); return; }
  idx -= 2048;
  if (idx < 2048) repack_one(pw3, BpP3, 128, 128, idx);
}

// ---------------------------------------------------------------------------
// Single-pass GAT aggregate over FP8 message rows (16 B/lane = 16 channels):
//  - direct col loads (same-address broadcast across the RL-lane sub-group)
//  - PD=2 double-buffered prefetch of (col, asrc, h-row16B)
//  - native v_cvt_pk_f32_fp8 decode + PACKED v_pk_fma_f32 accumulation
//    (8 cvt + 8 pk_fma per 16 ch instead of 8 cvt + 16 scalar fma)
// Then bias + LayerNorm + f16 residual + ELU -> f16.
template <int H, int C, int SPLIT>
__global__ __launch_bounds__(256) void gat_agg_kernel(
    const unsigned char* __restrict__ hfeat, const float* __restrict__ asrc,
    const float* __restrict__ adst, const int* __restrict__ rowptr,
    const int* __restrict__ col, const float* __restrict__ bias,
    const float* __restrict__ gamma, const float* __restrict__ beta,
    const unsigned short* __restrict__ proj, unsigned short* __restrict__ out, int N) {
  constexpr int DOUT = H * C;
  constexpr int RL = DOUT / 16;  // lanes covering one fp8 row at 16 B/lane
  static_assert(RL * SPLIT == 64, "bad split");
  constexpr int PD = 2;
  const int wave = threadIdx.x >> 6;
  const int lane = threadIdx.x & 63;
  const int n = blockIdx.x * 4 + wave;
  if (n >= N) return;
  const int rl = lane % RL;
  const int sub = lane / RL;
  const int c0 = rl * 16;  // channel == byte offset
  const int myh = c0 / C;
  const int start = rowptr[n];
  const int deg = rowptr[n + 1] - start;
  const int vlen = deg + 1;
  const int nsteps = (vlen + SPLIT - 1) / SPLIT;
  const int ngroups = (nsteps + PD - 1) / PD;
  const float my_adl = adst[n * H + myh];
  const int clmax = (deg > 0) ? deg - 1 : 0;

  f32x2 acc2[8] = {};
  float psum = 0.f;

  float aA[PD], aB[PD];
  uint4 hA[PD], hB[PD];

  auto issue = [&](int g, float* a, uint4* h) {
#pragma unroll
    for (int k = 0; k < PD; k++) {
      const int j = (g * PD + k) * SPLIT + sub;
      int s = col[start + min(j, clmax)];
      s = (j < deg) ? s : n;
      a[k] = asrc[s * H + myh];
      h[k] = *(const uint4*)&hfeat[(size_t)s * DOUT + c0];
    }
  };
  auto consume = [&](int g, const float* a, const uint4* h) {
#pragma unroll
    for (int k = 0; k < PD; k++) {
      const int j = (g * PD + k) * SPLIT + sub;
      float e = a[k] + my_adl;
      e = fmaxf(e, 0.2f * e);
      float p = __expf(e);
      p = (j < vlen) ? p : 0.f;
      psum += p;
      const f32x2 pv = {p, p};
      acc2[0] = __builtin_elementwise_fma(
          __builtin_amdgcn_cvt_pk_f32_fp8(h[k].x, false), pv, acc2[0]);
      acc2[1] = __builtin_elementwise_fma(
          __builtin_amdgcn_cvt_pk_f32_fp8(h[k].x, true), pv, acc2[1]);
      acc2[2] = __builtin_elementwise_fma(
          __builtin_amdgcn_cvt_pk_f32_fp8(h[k].y, false), pv, acc2[2]);
      acc2[3] = __builtin_elementwise_fma(
          __builtin_amdgcn_cvt_pk_f32_fp8(h[k].y, true), pv, acc2[3]);
      acc2[4] = __builtin_elementwise_fma(
          __builtin_amdgcn_cvt_pk_f32_fp8(h[k].z, false), pv, acc2[4]);
      acc2[5] = __builtin_elementwise_fma(
          __builtin_amdgcn_cvt_pk_f32_fp8(h[k].z, true), pv, acc2[5]);
      acc2[6] = __builtin_elementwise_fma(
          __builtin_amdgcn_cvt_pk_f32_fp8(h[k].w, false), pv, acc2[6]);
      acc2[7] = __builtin_elementwise_fma(
          __builtin_amdgcn_cvt_pk_f32_fp8(h[k].w, true), pv, acc2[7]);
    }
  };

  issue(0, aA, hA);
  for (int g = 0; g < ngroups; g += 2) {
    if (g + 1 < ngroups) issue(g + 1, aB, hB);
    consume(g, aA, hA);
    if (g + 1 < ngroups) {
      if (g + 2 < ngroups) issue(g + 2, aA, hA);
      consume(g + 1, aB, hB);
    }
  }

  float acc[16];
#pragma unroll
  for (int i = 0; i < 8; i++) {
    acc[2 * i] = acc2[i].x;
    acc[2 * i + 1] = acc2[i].y;
  }
  // combine SPLIT sub-wave partials
#pragma unroll
  for (int o = RL; o < 64; o <<= 1) {
    psum += __shfl_xor(psum, o);
#pragma unroll
    for (int i = 0; i < 16; i++) acc[i] += __shfl_xor(acc[i], o);
  }

  const float rs = 1.f / (psum + 1e-16f);
  float v[16];
#pragma unroll
  for (int q = 0; q < 4; q++) {
    const float4 bi = *(const float4*)&bias[c0 + q * 4];
    v[q * 4 + 0] = acc[q * 4 + 0] * rs + bi.x;
    v[q * 4 + 1] = acc[q * 4 + 1] * rs + bi.y;
    v[q * 4 + 2] = acc[q * 4 + 2] * rs + bi.z;
    v[q * 4 + 3] = acc[q * 4 + 3] * rs + bi.w;
  }
  float s16 = 0.f;
#pragma unroll
  for (int i = 0; i < 16; i++) s16 += v[i];
  const float mean = wave_sum(s16) / (float)(DOUT * SPLIT);
  float q16 = 0.f;
#pragma unroll
  for (int i = 0; i < 16; i++) {
    v[i] -= mean;
    q16 += v[i] * v[i];
  }
  const float var = wave_sum(q16) / (float)(DOUT * SPLIT);
  const float rstd = rsqrtf(var + 1e-5f);

  const uint4 pr0 = *(const uint4*)&proj[(size_t)n * DOUT + c0];
  const uint4 pr1 = *(const uint4*)&proj[(size_t)n * DOUT + c0 + 8];
  float pres[16];
  pres[0] = hlo(pr0.x); pres[1] = hhi(pr0.x); pres[2] = hlo(pr0.y); pres[3] = hhi(pr0.y);
  pres[4] = hlo(pr0.z); pres[5] = hhi(pr0.z); pres[6] = hlo(pr0.w); pres[7] = hhi(pr0.w);
  pres[8] = hlo(pr1.x); pres[9] = hhi(pr1.x); pres[10] = hlo(pr1.y); pres[11] = hhi(pr1.y);
  pres[12] = hlo(pr1.z); pres[13] = hhi(pr1.z); pres[14] = hlo(pr1.w); pres[15] = hhi(pr1.w);

  float o16[16];
#pragma unroll
  for (int q = 0; q < 4; q++) {
    const float4 ga = *(const float4*)&gamma[c0 + q * 4];
    const float4 be = *(const float4*)&beta[c0 + q * 4];
    o16[q * 4 + 0] = v[q * 4 + 0] * rstd * ga.x + be.x + pres[q * 4 + 0];
    o16[q * 4 + 1] = v[q * 4 + 1] * rstd * ga.y + be.y + pres[q * 4 + 1];
    o16[q * 4 + 2] = v[q * 4 + 2] * rstd * ga.z + be.z + pres[q * 4 + 2];
    o16[q * 4 + 3] = v[q * 4 + 3] * rstd * ga.w + be.w + pres[q * 4 + 3];
  }
#pragma unroll
  for (int i = 0; i < 16; i++)
    o16[i] = (o16[i] > 0.f) ? o16[i] : (__expf(o16[i]) - 1.f);  // ELU

  if (sub == 0) {
    uint4 ov0, ov1;
    ov0.x = (unsigned int)f2h(o16[0]) | ((unsigned int)f2h(o16[1]) << 16);
    ov0.y = (unsigned int)f2h(o16[2]) | ((unsigned int)f2h(o16[3]) << 16);
    ov0.z = (unsigned int)f2h(o16[4]) | ((unsigned int)f2h(o16[5]) << 16);
    ov0.w = (unsigned int)f2h(o16[6]) | ((unsigned int)f2h(o16[7]) << 16);
    ov1.x = (unsigned int)f2h(o16[8]) | ((unsigned int)f2h(o16[9]) << 16);
    ov1.y = (unsigned int)f2h(o16[10]) | ((unsigned int)f2h(o16[11]) << 16);
    ov1.z = (unsigned int)f2h(o16[12]) | ((unsigned int)f2h(o16[13]) << 16);
    ov1.w = (unsigned int)f2h(o16[14]) | ((unsigned int)f2h(o16[15]) << 16);
    *(uint4*)&out[(size_t)n * DOUT + c0] = ov0;
    *(uint4*)&out[(size_t)n * DOUT + c0 + 8] = ov1;
  }
}

// ---------------------------------------------------------------------------
// CSR build
__global__ void hist_kernel(const int* __restrict__ dst, int* __restrict__ cnt, int E) {
  const int e = blockIdx.x * 256 + threadIdx.x;
  if (e < E) atomicAdd(&cnt[dst[e]], 1);
}

__global__ __launch_bounds__(256) void scan1_kernel(int* __restrict__ cnt,
                                                    int* __restrict__ sums, int N) {
  __shared__ int sm[256];
  const int i = blockIdx.x * 256 + threadIdx.x;
  const int v = (i < N) ? cnt[i] : 0;
  sm[threadIdx.x] = v;
  __syncthreads();
  for (int off = 1; off < 256; off <<= 1) {
    const int t = (threadIdx.x >= off) ? sm[threadIdx.x - off] : 0;
    __syncthreads();
    sm[threadIdx.x] += t;
    __syncthreads();
  }
  if (i < N) cnt[i] = sm[threadIdx.x] - v;  // exclusive within block
  if (threadIdx.x == 255) sums[blockIdx.x] = sm[255];
}

// fused scan2+scan3: every block locally scans the block sums, then emits rowptr
__global__ __launch_bounds__(256) void scan23_kernel(const int* __restrict__ cnt,
                                                     const int* __restrict__ sums,
                                                     int* __restrict__ rowptr,
                                                     int* __restrict__ cursor, int N,
                                                     int E, int nb) {
  __shared__ int sm[256];
  const int v = (threadIdx.x < nb) ? sums[threadIdx.x] : 0;
  sm[threadIdx.x] = v;
  __syncthreads();
  for (int off = 1; off < 256; off <<= 1) {
    const int t = (threadIdx.x >= off) ? sm[threadIdx.x - off] : 0;
    __syncthreads();
    sm[threadIdx.x] += t;
    __syncthreads();
  }
  const int base = (blockIdx.x == 0) ? 0 : sm[blockIdx.x - 1];  // exclusive
  const int i = blockIdx.x * 256 + threadIdx.x;
  if (i < N) {
    const int r = cnt[i] + base;
    rowptr[i] = r;
    cursor[i] = r;
  }
  if (i == 0) rowptr[N] = E;
}

__global__ void scatter_kernel(const int* __restrict__ src, const int* __restrict__ dst,
                               int* __restrict__ cursor, int* __restrict__ col, int E) {
  const int e = blockIdx.x * 256 + threadIdx.x;
  if (e < E) {
    const int p = atomicAdd(&cursor[dst[e]], 1);
    col[p] = src[e];
  }
}

// ---------------------------------------------------------------------------
// Global mean pool per graph (batch sorted): one block per graph.
__global__ __launch_bounds__(128) void pool_kernel(const unsigned short* __restrict__ h3,
                                                   const int* __restrict__ batch,
                                                   float* __restrict__ out, int N) {
  __shared__ int sse[2];
  const int g = blockIdx.x;
  if (threadIdx.x == 0) {
    int lo = 0, hi = N;
    while (lo < hi) { const int mid = (lo + hi) >> 1; if (batch[mid] < g) lo = mid + 1; else hi = mid; }
    sse[0] = lo;
    lo = 0; hi = N;
    while (lo < hi) { const int mid = (lo + hi) >> 1; if (batch[mid] < g + 1) lo = mid + 1; else hi = mid; }
    sse[1] = lo;
  }
  __syncthreads();
  const int s = sse[0], e = sse[1];
  float sum = 0.f;
  for (int r = s; r < e; r++) sum += h2f(h3[(size_t)r * 128 + threadIdx.x]);
  out[g * 128 + threadIdx.x] = (e > s) ? sum / (float)(e - s) : 0.f;
}

// ---------------------------------------------------------------------------
extern "C" void kernel_launch(void* const* d_in, const int* in_sizes, int n_in,
                              void* d_out, int out_size, void* d_ws, size_t ws_size,
                              hipStream_t stream) {
  const float* x      = (const float*)d_in[0];
  const int* edge_idx = (const int*)d_in[1];
  const int* batch    = (const int*)d_in[2];
  const float* W1     = (const float*)d_in[3];
  const float* a_src1 = (const float*)d_in[4];
  const float* a_dst1 = (const float*)d_in[5];
  const float* b1     = (const float*)d_in[6];
  const float* g1     = (const float*)d_in[7];
  const float* be1    = (const float*)d_in[8];
  const float* pw1    = (const float*)d_in[9];
  const float* pb1    = (const float*)d_in[10];
  const float* W2     = (const float*)d_in[11];
  const float* a_src2 = (const float*)d_in[12];
  const float* a_dst2 = (const float*)d_in[13];
  const float* b2     = (const float*)d_in[14];
  const float* g2     = (const float*)d_in[15];
  const float* be2    = (const float*)d_in[16];
  const float* pw2    = (const float*)d_in[17];
  const float* pb2    = (const float*)d_in[18];
  const float* W3     = (const float*)d_in[19];
  const float* a_src3 = (const float*)d_in[20];
  const float* a_dst3 = (const float*)d_in[21];
  const float* b3     = (const float*)d_in[22];
  const float* g3     = (const float*)d_in[23];
  const float* be3    = (const float*)d_in[24];
  const float* pw3    = (const float*)d_in[25];
  const float* pb3    = (const float*)d_in[26];

  const int NN = in_sizes[0] / 128;  // 50000
  const int E  = in_sizes[1] / 2;    // 800000
  const int G  = out_size / 128;     // 512
  const int M64 = (NN + 63) & ~63;   // 50048

  size_t off = 0;
  auto alloc = [&](size_t bytes) {
    size_t r = off;
    off += (bytes + 255) & ~(size_t)255;
    return r;
  };
  char* ws = (char*)d_ws;
  unsigned char* hf    = (unsigned char*)(ws + alloc((size_t)M64 * 256));      // fp8 msg features (all layers)
  unsigned short* big1 = (unsigned short*)(ws + alloc((size_t)M64 * 256 * 2)); // h1out f16
  unsigned short* s0   = (unsigned short*)(ws + alloc((size_t)M64 * 128 * 2)); // xh / h3out f16
  unsigned short* s1   = (unsigned short*)(ws + alloc((size_t)M64 * 128 * 2)); // h2out f16
  unsigned short* projb = (unsigned short*)(ws + alloc((size_t)M64 * 256 * 2)); // f16 residual
  float* asrcB  = (float*)(ws + alloc((size_t)M64 * 8 * 4));
  float* adstB  = (float*)(ws + alloc((size_t)M64 * 8 * 4));
  float* asrc3B = (float*)(ws + alloc((size_t)M64 * 4));
  float* adst3B = (float*)(ws + alloc((size_t)M64 * 4));
  int* rowptr  = (int*)(ws + alloc((size_t)(NN + 1) * 4));
  int* cnt     = (int*)(ws + alloc((size_t)NN * 4));
  int* cursor  = (int*)(ws + alloc((size_t)NN * 4));
  int* colb    = (int*)(ws + alloc((size_t)(E + 64) * 4));  // +64 pad: clamped OOB reads
  int* sums    = (int*)(ws + alloc(256 * 4));
  unsigned short* BpW1 = (unsigned short*)(ws + alloc(128 * 256 * 2));
  unsigned short* BpP1 = (unsigned short*)(ws + alloc(128 * 256 * 2));
  unsigned short* BpW2 = (unsigned short*)(ws + alloc(256 * 128 * 2));
  unsigned short* BpP2 = (unsigned short*)(ws + alloc(256 * 128 * 2));
  unsigned short* BpW3 = (unsigned short*)(ws + alloc(128 * 128 * 2));
  unsigned short* BpP3 = (unsigned short*)(ws + alloc(128 * 128 * 2));
  (void)ws_size; (void)n_in;

  const int EB = (E + 255) / 256;
  const int NB = (NN + 255) / 256;  // 196
  const int NW = (NN + 3) / 4;
  const int MB = M64 / 64;
  const int pad = M64 - NN;

  // ---- init: cast + all zeroing + all repacks in one dispatch ----
  const int initN = M64 * 32 + NN + pad * 32 + pad * 16 + 2 * (M64 / 4) + 20480;
  init_kernel<<<(initN + 255) / 256, 256, 0, stream>>>(
      x, s0, NN * 32, NN, M64, pad, cnt, big1 + (size_t)NN * 256,
      s1 + (size_t)NN * 128, asrc3B, adst3B, W1, pw1, W2, pw2, W3, pw3, BpW1, BpP1,
      BpW2, BpP2, BpW3, BpP3);

  // ---- CSR build (dst-sorted adjacency), reused by all 3 layers ----
  hist_kernel<<<EB, 256, 0, stream>>>(edge_idx + E, cnt, E);
  scan1_kernel<<<NB, 256, 0, stream>>>(cnt, sums, NN);
  scan23_kernel<<<NB, 256, 0, stream>>>(cnt, sums, rowptr, cursor, NN, E, NB);
  scatter_kernel<<<EB, 256, 0, stream>>>(edge_idx, edge_idx + E, cursor, colb, E);

  // ---- Layer 1: 128 -> 8x32 = 256 ----
  fused_gemm_kernel<128, 32, 8, false><<<dim3(4, MB), 256, 0, stream>>>(
      s0, BpW1, BpP1, pb1, a_src1, a_dst1, hf, projb, asrcB, adstB, 256);
  gat_agg_kernel<8, 32, 4><<<NW, 256, 0, stream>>>(hf, asrcB, adstB, rowptr, colb,
                                                   b1, g1, be1, projb, big1, NN);
  // big1 = h1 (f16)

  // ---- Layer 2: 256 -> 4x32 = 128 ----
  fused_gemm_kernel<256, 32, 4, false><<<dim3(2, MB), 256, 0, stream>>>(
      big1, BpW2, BpP2, pb2, a_src2, a_dst2, hf, projb, asrcB, adstB, 128);
  gat_agg_kernel<4, 32, 8><<<NW, 256, 0, stream>>>(hf, asrcB, adstB, rowptr, colb,
                                                   b2, g2, be2, projb, s1, NN);
  // s1 = h2 (f16)

  // ---- Layer 3: 128 -> 1x128 (concat=False; 1 head -> identity mean) ----
  fused_gemm_kernel<128, 128, 1, true><<<dim3(2, MB), 256, 0, stream>>>(
      s1, BpW3, BpP3, pb3, a_src3, a_dst3, hf, projb, asrc3B, adst3B, 128);
  gat_agg_kernel<1, 128, 8><<<NW, 256, 0, stream>>>(hf, asrc3B, adst3B, rowptr, colb,
                                                    b3, g3, be3, projb, s0, NN);
  // s0 = h3 (f16)

  // ---- Global mean pool per graph ----
  pool_kernel<<<G, 128, 0, stream>>>(s0, batch, (float*)d_out, NN);
}